// Round 12
// baseline (773.398 us; speedup 1.0000x reference)
//
#include <hip/hip_runtime.h>
#include <hip/hip_bf16.h>
#include <math.h>

#define B_ 2
#define L_ 4096
#define D_ 1024
#define DIN 2048
#define DPROJ 4160
#define CONVD 2080
#define H_ 32
#define P_ 64
#define N_ 16
#define K_ 4
#define M_ROWS (B_*L_)

// chunked scan: NC chunks of CH steps
#define NC 64
#define CH 64

typedef __bf16 bf16_8 __attribute__((ext_vector_type(8)));
typedef float f32x4 __attribute__((ext_vector_type(4)));

// async global->LDS, 16 B per lane; LDS dest = wave-uniform base + lane*16
__device__ __forceinline__ void gload_lds16(const void* g, void* l) {
    __builtin_amdgcn_global_load_lds(
        (const __attribute__((address_space(1))) unsigned int*)g,
        (__attribute__((address_space(3))) unsigned int*)l, 16, 0, 0);
}

// ---------------- fp32 -> bf16 weight conversion ----------------
__global__ __launch_bounds__(256) void cvt_kernel(const float* __restrict__ src,
        __bf16* __restrict__ dst, int n) {
    int i = (blockIdx.x*256 + threadIdx.x)*8;
    if (i < n) {
        float4 f0 = *(const float4*)(src + i);
        float4 f1 = *(const float4*)(src + i + 4);
        bf16_8 o;
        o[0]=(__bf16)f0.x; o[1]=(__bf16)f0.y; o[2]=(__bf16)f0.z; o[3]=(__bf16)f0.w;
        o[4]=(__bf16)f1.x; o[5]=(__bf16)f1.y; o[6]=(__bf16)f1.z; o[7]=(__bf16)f1.w;
        *(bf16_8*)(dst + i) = o;
    }
}

// ---------------- RMSNorm (in fp32, out bf16) ----------------
template<typename TI>
__global__ __launch_bounds__(256) void rms_kernel(const TI* __restrict__ x,
        const float* __restrict__ w, __bf16* __restrict__ out) {
    int row = blockIdx.x;
    int tid = threadIdx.x;
    const TI* xr = x + (size_t)row * D_;
    float v[4];
    float ss = 0.f;
#pragma unroll
    for (int i = 0; i < 4; i++) {
        v[i] = (float)xr[tid*4 + i];
        ss += v[i]*v[i];
    }
#pragma unroll
    for (int off = 32; off >= 1; off >>= 1) ss += __shfl_xor(ss, off, 64);
    __shared__ float sred[4];
    int wave = tid >> 6;
    if ((tid & 63) == 0) sred[wave] = ss;
    __syncthreads();
    ss = sred[0] + sred[1] + sred[2] + sred[3];
    float scale = rsqrtf(ss * (1.f/(float)D_) + 1e-6f);
#pragma unroll
    for (int i = 0; i < 4; i++)
        out[(size_t)row*D_ + tid*4 + i] = (__bf16)(v[i] * scale * w[tid*4 + i]);
}

// ---------------- GEMM (128x128, BK=64 as 2x32 sub-blocks): C = A @ W^T --------
// R9 verdict: BK=128 regressed (occupancy 26->20.6%) — BK=64 is this
// structure's optimum (R6: fc1 126->103us). GEMM lane closed at ~700 TF eff.
// EPI 0: bf16 | EPI 2/4: +bias+resid -> fp32 | EPI 3: +bias, gelu -> bf16
#define BM 128
#define BN 128
#define BK 64

template<int EPI>
__global__ __launch_bounds__(256) void gemm_kernel(
    const __bf16* __restrict__ A, const __bf16* __restrict__ W,
    void* __restrict__ Cout, const float* __restrict__ bias,
    const float* __restrict__ resid, int M, int N, int K)
{
    __shared__ __attribute__((aligned(16))) __bf16 As[2][BM][32];   // 16 KB
    __shared__ __attribute__((aligned(16))) __bf16 Bs[2][BN][32];   // 16 KB
    int tid = threadIdx.x;
    int lane = tid & 63, wave = tid >> 6;
    int wm = wave >> 1, wn = wave & 1;
    int quad = lane >> 4, l16 = lane & 15;

    // grouped raster: groups of 8 M-blocks share the N-sweep
    int num_n = gridDim.x, num_m = gridDim.y;
    int pid = blockIdx.y * num_n + blockIdx.x;
    const int G = 8;
    int gsz = G * num_n;
    int grp = pid / gsz;
    int rem = pid - grp * gsz;
    int first_m = grp * G;
    int gm = (num_m - first_m < G) ? (num_m - first_m) : G;
    int m_idx = first_m + rem % gm;
    int n_idx = rem / gm;
    int bm0 = m_idx * BM, bn0 = n_idx * BN;

    int srow = lane >> 2;   // 0..15 row within 16-row chunk
    int sseg = lane & 3;    // 16 B (8 bf16) segment within 32-col sub-row

    f32x4 acc[4][4] = {};

    for (int kk = 0; kk < K; kk += BK) {
#pragma unroll
        for (int kh = 0; kh < 2; kh++) {
#pragma unroll
            for (int k = 0; k < 2; k++) {
                int c = wave*2 + k;                 // chunk 0..7 (16 rows each)
                int arow = bm0 + c*16 + srow;
                gload_lds16(A + (size_t)arow*K + kk + kh*32 + sseg*8,
                            (char*)&As[kh][0][0] + c*1024);
                int nr = bn0 + c*16 + srow;
                if (nr < N)
                    gload_lds16(W + (size_t)nr*K + kk + kh*32 + sseg*8,
                                (char*)&Bs[kh][0][0] + c*1024);
            }
        }
        __syncthreads();
#pragma unroll
        for (int kh = 0; kh < 2; kh++) {
            bf16_8 af[4], bfr[4];
#pragma unroll
            for (int i = 0; i < 4; i++) {
                af[i]  = *(const bf16_8*)&As[kh][wm*64 + i*16 + l16][quad*8];
                bfr[i] = *(const bf16_8*)&Bs[kh][wn*64 + i*16 + l16][quad*8];
            }
#pragma unroll
            for (int mi = 0; mi < 4; mi++)
#pragma unroll
                for (int ni = 0; ni < 4; ni++)
                    acc[mi][ni] = __builtin_amdgcn_mfma_f32_16x16x32_bf16(af[mi], bfr[ni], acc[mi][ni], 0, 0, 0);
        }
        __syncthreads();
    }

#pragma unroll
    for (int mi = 0; mi < 4; mi++) {
        int mbase = bm0 + wm*64 + mi*16 + quad*4;
#pragma unroll
        for (int ni = 0; ni < 4; ni++) {
            int n = bn0 + wn*64 + ni*16 + l16;
            if (n < N) {
#pragma unroll
                for (int r = 0; r < 4; r++) {
                    size_t idx = (size_t)(mbase + r)*N + n;
                    float v = acc[mi][ni][r];
                    if constexpr (EPI == 0) {
                        ((__bf16*)Cout)[idx] = (__bf16)v;
                    } else if constexpr (EPI == 2) {
                        v += bias[n] + resid[idx];
                        ((float*)Cout)[idx] = v;
                    } else if constexpr (EPI == 3) {
                        v += bias[n];
                        // gelu(tanh) = v*sigmoid(1.5957691216*(v+0.044715 v^3))
                        float u = 1.5957691216057308f*(v + 0.044715f*v*v*v);
                        float g = v * __builtin_amdgcn_rcpf(1.f + __expf(-u));
                        ((__bf16*)Cout)[idx] = (__bf16)g;
                    } else if constexpr (EPI == 4) {
                        v += bias[n] + resid[idx];
                        ((float*)Cout)[idx] = v;
                    }
                }
            }
        }
    }
}

// ---------------- depthwise causal conv (K=4) + SiLU, x8 vectorized ----------
// R12: was 4 scalar bf16 loads/thread (Common-mistake #2). Now each thread
// handles 8 consecutive channels: 4x bf16_8 loads (16B aligned: (DIN+8g)*2),
// float4 weight loads, vector stores. Same k-accumulation order -> bit-identical.
__global__ __launch_bounds__(256) void conv_kernel(
    const __bf16* __restrict__ proj, const float* __restrict__ cw,
    const float* __restrict__ cb, __bf16* __restrict__ u_out,
    float* __restrict__ bc_out)
{
    int idx = blockIdx.x*256 + threadIdx.x;     // B_*L_*260 total, 260 = CONVD/8
    if (idx >= B_*L_*(CONVD/8)) return;
    int g   = idx % (CONVD/8);
    int row = idx / (CONVD/8);                  // b*L_ + t
    int t   = row & (L_-1);
    int c0  = g*8;

    float acc[8];
#pragma unroll
    for (int j = 0; j < 8; j++) acc[j] = cb[c0 + j];

#pragma unroll
    for (int k = 0; k < K_; k++) {
        int tt = t + k - (K_-1);
        if (tt >= 0) {
            bf16_8 pv = *(const bf16_8*)&proj[(size_t)(row + k - (K_-1))*DPROJ + DIN + c0];
#pragma unroll
            for (int j = 0; j < 8; j++)
                acc[j] += (float)pv[j] * cw[(c0 + j)*K_ + k];
        }
    }

    float s[8];
#pragma unroll
    for (int j = 0; j < 8; j++)
        s[j] = acc[j] / (1.f + __expf(-acc[j]));

    if (c0 < DIN) {
        bf16_8 o;
#pragma unroll
        for (int j = 0; j < 8; j++) o[j] = (__bf16)s[j];
        *(bf16_8*)&u_out[(size_t)row*DIN + c0] = o;
    } else {
        int cb0 = c0 - DIN;                     // 0, 8, 16, 24
        float4 f0 = {s[0], s[1], s[2], s[3]};
        float4 f1 = {s[4], s[5], s[6], s[7]};
        *(float4*)&bc_out[(size_t)row*32 + cb0]     = f0;
        *(float4*)&bc_out[(size_t)row*32 + cb0 + 4] = f1;
    }
}

// ---------------- B/C normalize + softplus(dt) ----------------
__global__ __launch_bounds__(64) void prep_kernel(
    const float* __restrict__ bc, const __bf16* __restrict__ proj,
    const float* __restrict__ dt_bias,
    float* __restrict__ Bn, float* __restrict__ Cn, float* __restrict__ dtv)
{
    int row = blockIdx.x;
    int tid = threadIdx.x;
    if (tid < 32) {
        float v = bc[(size_t)row*32 + tid];
        float ss = v*v;
        ss += __shfl_xor(ss, 1, 16);
        ss += __shfl_xor(ss, 2, 16);
        ss += __shfl_xor(ss, 4, 16);
        ss += __shfl_xor(ss, 8, 16);
        float nv = v * rsqrtf(ss + 1e-6f);
        if (tid < 16) Bn[(size_t)row*16 + tid] = nv;
        else Cn[(size_t)row*16 + (tid-16)] = nv;
    } else {
        int h = tid - 32;
        float xv = (float)proj[(size_t)row*DPROJ + 2*DIN + 2*N_ + h] + dt_bias[h];
        float sp = (xv > 20.f) ? xv : log1pf(__expf(xv));
        dtv[(size_t)row*32 + h] = sp;
    }
}

// ================= chunked parallel scan =================
__global__ __launch_bounds__(64) void scan_phase0(
    const float* __restrict__ dtv, const float* __restrict__ A_param,
    float* __restrict__ Mprod)
{
    int blk = blockIdx.x;
    int cg = blk & 15;
    int h  = (blk >> 4) & 31;
    int b  = blk >> 9;
    int lane = threadIdx.x;
    int n  = lane & 15;
    int c  = cg*4 + (lane >> 4);
    int bh = b*32 + h;

    float Av = fmaxf(A_param[h*16 + n], 0.f);
    float P00 = 1.f, P01 = 0.f, P10 = 0.f, P11 = 1.f;
    size_t r0 = (size_t)b*L_ + (size_t)c*CH;

#pragma unroll 4
    for (int tt = 0; tt < CH; tt++) {
        float d  = dtv[(r0 + tt)*32 + h];
        float rc = __builtin_amdgcn_rcpf(fmaf(d*d, Av, 1.f));
        float da = d*Av;
        float n00 = rc*fmaf(-da, P10, P00);
        float n01 = rc*fmaf(-da, P11, P01);
        float n10 = rc*fmaf(d, P00, P10);
        float n11 = rc*fmaf(d, P01, P11);
        P00=n00; P01=n01; P10=n10; P11=n11;
    }

    size_t mi = (((size_t)bh*NC + c)*16 + n)*4;
    Mprod[mi+0]=P00; Mprod[mi+1]=P01; Mprod[mi+2]=P10; Mprod[mi+3]=P11;
}

// R10 form (LDS rc/d tables) + R11 unroll 8; R12: single full-grid dispatch
__global__ __launch_bounds__(64) void scan_phase1(
    const float* __restrict__ dtv, const float* __restrict__ Bn,
    const __bf16* __restrict__ u, const float* __restrict__ A_param,
    float* __restrict__ vbuf)
{
    __shared__ float rcT[CH][16];   // 4 KB
    __shared__ float dT[CH];        // 256 B
    int blk = blockIdx.x;
    int c  = blk & (NC-1);
    int pg = (blk >> 6) & 3;
    int h  = (blk >> 8) & 31;
    int b  = blk >> 13;
    int lane = threadIdx.x;
    int pl = lane >> 2, nq = lane & 3;
    int p = pg*16 + pl;
    int ch = h*64 + p;
    int bh = b*32 + h;

    size_t r0 = (size_t)b*L_ + (size_t)c*CH;

    // table build: lane tt computes rc for its timestep (bit-identical ops)
    {
        float d = dtv[(r0 + lane)*32 + h];
        dT[lane] = d;
        float dd = d*d;
#pragma unroll
        for (int n = 0; n < 16; n++) {
            float Avn = fmaxf(A_param[h*16 + n], 0.f);
            rcT[lane][n] = __builtin_amdgcn_rcpf(fmaf(dd, Avn, 1.f));
        }
    }
    __syncthreads();

    float Av[4];
#pragma unroll
    for (int j = 0; j < 4; j++) Av[j] = fmaxf(A_param[h*16 + nq*4 + j], 0.f);

    float z[4] = {}, y[4] = {};

#pragma unroll 8
    for (int tt = 0; tt < CH; tt++) {
        size_t rn = r0 + tt;
        float d  = dT[tt];
        float4 rc4 = *(const float4*)&rcT[tt][nq*4];
        float4 Bv = *(const float4*)&Bn[rn*16 + nq*4];
        float up = (float)u[rn*DIN + ch];
        float rcj[4] = {rc4.x, rc4.y, rc4.z, rc4.w};
        float Bvj[4] = {Bv.x, Bv.y, Bv.z, Bv.w};
#pragma unroll
        for (int j = 0; j < 4; j++) {
            float q = fmaf(-Av[j], y[j], up*Bvj[j]);
            float zn = fmaf(d, q, z[j]) * rcj[j];
            z[j] = zn;
            y[j] = fmaf(d, zn, y[j]);
        }
    }

    size_t vb = ((size_t)bh*NC + c)*16;
#pragma unroll
    for (int j = 0; j < 4; j++) {
        int n = nq*4 + j;
        size_t vi = ((vb + n)*64 + p)*2;
        vbuf[vi]   = z[j];
        vbuf[vi+1] = y[j];
    }
}

// n-parallel phase2 (R11): 1024 blocks, one (bh,n) chain each; bit-identical.
__global__ __launch_bounds__(64) void scan_phase2(
    float* __restrict__ vbuf, const float* __restrict__ Mprod)
{
    int blk = blockIdx.x;
    int bh = blk >> 4;
    int n  = blk & 15;
    int p = threadIdx.x;
    float z = 0.f, y = 0.f;
#pragma unroll 4
    for (int c = 0; c < NC; c++) {
        size_t base = ((size_t)bh*NC + c)*16 + n;
        float4 mm = *(const float4*)&Mprod[base*4];
        size_t vi = (base*64 + p)*2;
        float vz = vbuf[vi], vy = vbuf[vi+1];
        vbuf[vi]   = z;
        vbuf[vi+1] = y;
        float zn = mm.x*z + mm.y*y + vz;
        float yn = mm.z*z + mm.w*y + vy;
        z = zn; y = yn;
    }
}

__global__ __launch_bounds__(64) void scan_phase3(
    const float* __restrict__ dtv, const float* __restrict__ Bn,
    const float* __restrict__ Cn, const __bf16* __restrict__ u,
    const __bf16* __restrict__ proj, const float* __restrict__ A_param,
    const float* __restrict__ D_skip, const float* __restrict__ vbuf,
    __bf16* __restrict__ y2)
{
    __shared__ float rcT[CH][16];   // 4 KB
    __shared__ float dT[CH];        // 256 B
    int blk = blockIdx.x;
    int c  = blk & (NC-1);
    int pg = (blk >> 6) & 3;
    int h  = (blk >> 8) & 31;
    int b  = blk >> 13;
    int lane = threadIdx.x;
    int pl = lane >> 2, nq = lane & 3;
    int p = pg*16 + pl;
    int ch = h*64 + p;
    int bh = b*32 + h;

    size_t r0 = (size_t)b*L_ + (size_t)c*CH;

    // table build (bit-identical rc)
    {
        float d = dtv[(r0 + lane)*32 + h];
        dT[lane] = d;
        float dd = d*d;
#pragma unroll
        for (int n = 0; n < 16; n++) {
            float Avn = fmaxf(A_param[h*16 + n], 0.f);
            rcT[lane][n] = __builtin_amdgcn_rcpf(fmaf(dd, Avn, 1.f));
        }
    }
    __syncthreads();

    float Av[4];
#pragma unroll
    for (int j = 0; j < 4; j++) Av[j] = fmaxf(A_param[h*16 + nq*4 + j], 0.f);
    float Dsk = D_skip[h];

    float z[4], y[4];
    size_t vb = ((size_t)bh*NC + c)*16;
#pragma unroll
    for (int j = 0; j < 4; j++) {
        int n = nq*4 + j;
        size_t vi = ((vb + n)*64 + p)*2;
        z[j] = vbuf[vi];
        y[j] = vbuf[vi+1];
    }

#pragma unroll 8
    for (int tt = 0; tt < CH; tt++) {
        size_t rn = r0 + tt;
        float d  = dT[tt];
        float4 rc4 = *(const float4*)&rcT[tt][nq*4];
        float4 Bv = *(const float4*)&Bn[rn*16 + nq*4];
        float4 Cv = *(const float4*)&Cn[rn*16 + nq*4];
        float up = (float)u[rn*DIN + ch];
        float zg = (float)proj[rn*DPROJ + ch];
        float rcj[4] = {rc4.x, rc4.y, rc4.z, rc4.w};
        float Bvj[4] = {Bv.x, Bv.y, Bv.z, Bv.w};
        float Cvj[4] = {Cv.x, Cv.y, Cv.z, Cv.w};
        float s = 0.f;
#pragma unroll
        for (int j = 0; j < 4; j++) {
            float q = fmaf(-Av[j], y[j], up*Bvj[j]);
            float zn = fmaf(d, q, z[j]) * rcj[j];
            z[j] = zn;
            y[j] = fmaf(d, zn, y[j]);
            s = fmaf(y[j], Cvj[j], s);
        }
        s += __shfl_xor(s, 1, 64);
        s += __shfl_xor(s, 2, 64);
        if (nq == 0) {
            float sig = __builtin_amdgcn_rcpf(1.f + __expf(-zg));
            y2[rn*DIN + ch] = (__bf16)((s + Dsk*up) * (zg * sig));
        }
    }
}

extern "C" void kernel_launch(void* const* d_in, const int* in_sizes, int n_in,
                              void* d_out, int out_size, void* d_ws, size_t ws_size,
                              hipStream_t stream) {
    const float* x         = (const float*)d_in[0];
    const float* norm1_w   = (const float*)d_in[1];
    const float* in_proj_w = (const float*)d_in[2];
    const float* conv_w    = (const float*)d_in[3];
    const float* conv_b    = (const float*)d_in[4];
    const float* A_param   = (const float*)d_in[5];
    const float* dt_bias   = (const float*)d_in[6];
    const float* D_skip    = (const float*)d_in[7];
    const float* out_proj_w= (const float*)d_in[8];
    const float* out_proj_b= (const float*)d_in[9];
    const float* norm2_w   = (const float*)d_in[10];
    const float* fc1_w     = (const float*)d_in[11];
    const float* fc1_b     = (const float*)d_in[12];
    const float* fc2_w     = (const float*)d_in[13];
    const float* fc2_b     = (const float*)d_in[14];
    float* out = (float*)d_out;

    // -------- workspace layout with lifetime-based aliasing (~148 MB) --------
    char* ws = (char*)d_ws;
    const size_t R0 = 0;
    const size_t R0_SZ = (size_t)M_ROWS*DPROJ*2;               // 68,157,440
    const size_t R1 = R0_SZ;
    const size_t R1_SZ = (size_t)M_ROWS*4*D_*2;                 // 67,108,864
    const size_t R2 = R1 + R1_SZ;                               // 135,266,304

    __bf16* proj   = (__bf16*)(ws + R0);
    float*  x2     = (float*) (ws + R0);                        // aliases proj (dead)
    __bf16* x2n    = (__bf16*)(ws + R0 + (size_t)M_ROWS*D_*4);
    __bf16* xn     = (__bf16*)(ws + R1);
    __bf16* y2     = (__bf16*)(ws + R1);                        // aliases xn (dead)
    __bf16* u_conv = (__bf16*)(ws + R1 + (size_t)M_ROWS*DIN*2);
    __bf16* h1     = (__bf16*)(ws + R1);                        // aliases y2+u_conv (dead)
    float*  bcraw  = (float*)(ws + R2);                                       // 1 MB
    float*  Bn     = (float*)(ws + R2 + (size_t)M_ROWS*32*4);                 // 0.5 MB
    float*  Cn     = (float*)(ws + R2 + (size_t)M_ROWS*32*4 + (size_t)M_ROWS*16*4);
    float*  dtv    = (float*)(ws + R2 + (size_t)M_ROWS*32*4 + (size_t)M_ROWS*16*4*2);
    float*  Mprod  = (float*)(ws + R2 + (size_t)M_ROWS*32*4*2 + (size_t)M_ROWS*16*4*2); // 1 MB
    __bf16* Wb     = (__bf16*)(ws + R2 + (size_t)M_ROWS*32*4*2 + (size_t)M_ROWS*16*4*2
                                 + (size_t)64*64*16*4*4);       // 8.52 MB slot, reused per GEMM

    float* vbuf = (float*)d_out;   // scan scratch; fully overwritten by fc2 GEMM

    // 1. RMSNorm1 (fp32 x -> bf16 xn)
    rms_kernel<float><<<M_ROWS, 256, 0, stream>>>(x, norm1_w, xn);

    // 2. in_proj GEMM: proj = xn @ in_proj_w^T
    {
        int n = DPROJ*D_;
        cvt_kernel<<<(n/8 + 255)/256, 256, 0, stream>>>(in_proj_w, Wb, n);
        dim3 grid((DPROJ + BN - 1)/BN, M_ROWS/BM);
        gemm_kernel<0><<<grid, 256, 0, stream>>>(xn, Wb, proj, nullptr, nullptr,
                                                 M_ROWS, DPROJ, D_);
    }

    // 3. conv + silu (x8 vectorized)
    {
        int total = B_*L_*(CONVD/8);   // 2,129,920
        conv_kernel<<<(total + 255)/256, 256, 0, stream>>>(proj, conv_w, conv_b, u_conv, bcraw);
    }

    // 4. B/C normalize + dt softplus
    prep_kernel<<<M_ROWS, 64, 0, stream>>>(bcraw, proj, dt_bias, Bn, Cn, dtv);

    // 5. chunked scan
    {
        int full = B_*H_*4*NC;   // 16384
        scan_phase0<<<B_*H_*16, 64, 0, stream>>>(dtv, A_param, Mprod);
        scan_phase1<<<full, 64, 0, stream>>>(dtv, Bn, u_conv, A_param, vbuf);
        scan_phase2<<<B_*H_*16, 64, 0, stream>>>(vbuf, Mprod);
        scan_phase3<<<full, 64, 0, stream>>>(dtv, Bn, Cn, u_conv, proj, A_param, D_skip,
                                             vbuf, y2);
    }

    // 6. out_proj GEMM + bias + residual(x) -> x2 (fp32, overwrites dead proj)
    {
        int n = D_*DIN;
        cvt_kernel<<<(n/8 + 255)/256, 256, 0, stream>>>(out_proj_w, Wb, n);
        dim3 grid((D_ + BN - 1)/BN, M_ROWS/BM);
        gemm_kernel<2><<<grid, 256, 0, stream>>>(y2, Wb, x2, out_proj_b, x, M_ROWS, D_, DIN);
    }

    // 7. RMSNorm2
    rms_kernel<float><<<M_ROWS, 256, 0, stream>>>(x2, norm2_w, x2n);

    // 8. fc1 GEMM + bias + gelu -> h1 (overwrites dead y2/u_conv)
    {
        int n = 4*D_*D_;
        cvt_kernel<<<(n/8 + 255)/256, 256, 0, stream>>>(fc1_w, Wb, n);
        dim3 grid((4*D_ + BN - 1)/BN, M_ROWS/BM);
        gemm_kernel<3><<<grid, 256, 0, stream>>>(x2n, Wb, h1, fc1_b, nullptr, M_ROWS, 4*D_, D_);
    }

    // 9. fc2 GEMM + bias + residual(x2) -> out (fp32)
    {
        int n = D_*4*D_;
        cvt_kernel<<<(n/8 + 255)/256, 256, 0, stream>>>(fc2_w, Wb, n);
        dim3 grid((D_ + BN - 1)/BN, M_ROWS/BM);
        gemm_kernel<4><<<grid, 256, 0, stream>>>(h1, Wb, out, fc2_b, x2, M_ROWS, D_, 4*D_);
    }
}

// Round 13
// 697.118 us; speedup vs baseline: 1.1094x; 1.1094x over previous
//
#include <hip/hip_runtime.h>
#include <hip/hip_bf16.h>
#include <math.h>

#define B_ 2
#define L_ 4096
#define D_ 1024
#define DIN 2048
#define DPROJ 4160
#define CONVD 2080
#define H_ 32
#define P_ 64
#define N_ 16
#define K_ 4
#define M_ROWS (B_*L_)

// chunked scan: NC chunks of CH steps
#define NC 64
#define CH 64

typedef __bf16 bf16_8 __attribute__((ext_vector_type(8)));
typedef float f32x4 __attribute__((ext_vector_type(4)));

// async global->LDS, 16 B per lane; LDS dest = wave-uniform base + lane*16
__device__ __forceinline__ void gload_lds16(const void* g, void* l) {
    __builtin_amdgcn_global_load_lds(
        (const __attribute__((address_space(1))) unsigned int*)g,
        (__attribute__((address_space(3))) unsigned int*)l, 16, 0, 0);
}

// ---------------- fp32 -> bf16 weight conversion ----------------
__global__ __launch_bounds__(256) void cvt_kernel(const float* __restrict__ src,
        __bf16* __restrict__ dst, int n) {
    int i = (blockIdx.x*256 + threadIdx.x)*8;
    if (i < n) {
        float4 f0 = *(const float4*)(src + i);
        float4 f1 = *(const float4*)(src + i + 4);
        bf16_8 o;
        o[0]=(__bf16)f0.x; o[1]=(__bf16)f0.y; o[2]=(__bf16)f0.z; o[3]=(__bf16)f0.w;
        o[4]=(__bf16)f1.x; o[5]=(__bf16)f1.y; o[6]=(__bf16)f1.z; o[7]=(__bf16)f1.w;
        *(bf16_8*)(dst + i) = o;
    }
}

// ---------------- RMSNorm (in fp32, out bf16) ----------------
template<typename TI>
__global__ __launch_bounds__(256) void rms_kernel(const TI* __restrict__ x,
        const float* __restrict__ w, __bf16* __restrict__ out) {
    int row = blockIdx.x;
    int tid = threadIdx.x;
    const TI* xr = x + (size_t)row * D_;
    float v[4];
    float ss = 0.f;
#pragma unroll
    for (int i = 0; i < 4; i++) {
        v[i] = (float)xr[tid*4 + i];
        ss += v[i]*v[i];
    }
#pragma unroll
    for (int off = 32; off >= 1; off >>= 1) ss += __shfl_xor(ss, off, 64);
    __shared__ float sred[4];
    int wave = tid >> 6;
    if ((tid & 63) == 0) sred[wave] = ss;
    __syncthreads();
    ss = sred[0] + sred[1] + sred[2] + sred[3];
    float scale = rsqrtf(ss * (1.f/(float)D_) + 1e-6f);
#pragma unroll
    for (int i = 0; i < 4; i++)
        out[(size_t)row*D_ + tid*4 + i] = (__bf16)(v[i] * scale * w[tid*4 + i]);
}

// ---------------- GEMM (128x128, BK=64 as 2x32 sub-blocks): C = A @ W^T --------
// R9 verdict: BK=128 regressed (occupancy 26->20.6%) — BK=64 is this
// structure's optimum (R6: fc1 126->103us). GEMM lane closed at ~700 TF eff.
// EPI 0: bf16 | EPI 2/4: +bias+resid -> fp32 | EPI 3: +bias, gelu -> bf16
#define BM 128
#define BN 128
#define BK 64

template<int EPI>
__global__ __launch_bounds__(256) void gemm_kernel(
    const __bf16* __restrict__ A, const __bf16* __restrict__ W,
    void* __restrict__ Cout, const float* __restrict__ bias,
    const float* __restrict__ resid, int M, int N, int K)
{
    __shared__ __attribute__((aligned(16))) __bf16 As[2][BM][32];   // 16 KB
    __shared__ __attribute__((aligned(16))) __bf16 Bs[2][BN][32];   // 16 KB
    int tid = threadIdx.x;
    int lane = tid & 63, wave = tid >> 6;
    int wm = wave >> 1, wn = wave & 1;
    int quad = lane >> 4, l16 = lane & 15;

    // grouped raster: groups of 8 M-blocks share the N-sweep
    int num_n = gridDim.x, num_m = gridDim.y;
    int pid = blockIdx.y * num_n + blockIdx.x;
    const int G = 8;
    int gsz = G * num_n;
    int grp = pid / gsz;
    int rem = pid - grp * gsz;
    int first_m = grp * G;
    int gm = (num_m - first_m < G) ? (num_m - first_m) : G;
    int m_idx = first_m + rem % gm;
    int n_idx = rem / gm;
    int bm0 = m_idx * BM, bn0 = n_idx * BN;

    int srow = lane >> 2;   // 0..15 row within 16-row chunk
    int sseg = lane & 3;    // 16 B (8 bf16) segment within 32-col sub-row

    f32x4 acc[4][4] = {};

    for (int kk = 0; kk < K; kk += BK) {
#pragma unroll
        for (int kh = 0; kh < 2; kh++) {
#pragma unroll
            for (int k = 0; k < 2; k++) {
                int c = wave*2 + k;                 // chunk 0..7 (16 rows each)
                int arow = bm0 + c*16 + srow;
                gload_lds16(A + (size_t)arow*K + kk + kh*32 + sseg*8,
                            (char*)&As[kh][0][0] + c*1024);
                int nr = bn0 + c*16 + srow;
                if (nr < N)
                    gload_lds16(W + (size_t)nr*K + kk + kh*32 + sseg*8,
                                (char*)&Bs[kh][0][0] + c*1024);
            }
        }
        __syncthreads();
#pragma unroll
        for (int kh = 0; kh < 2; kh++) {
            bf16_8 af[4], bfr[4];
#pragma unroll
            for (int i = 0; i < 4; i++) {
                af[i]  = *(const bf16_8*)&As[kh][wm*64 + i*16 + l16][quad*8];
                bfr[i] = *(const bf16_8*)&Bs[kh][wn*64 + i*16 + l16][quad*8];
            }
#pragma unroll
            for (int mi = 0; mi < 4; mi++)
#pragma unroll
                for (int ni = 0; ni < 4; ni++)
                    acc[mi][ni] = __builtin_amdgcn_mfma_f32_16x16x32_bf16(af[mi], bfr[ni], acc[mi][ni], 0, 0, 0);
        }
        __syncthreads();
    }

#pragma unroll
    for (int mi = 0; mi < 4; mi++) {
        int mbase = bm0 + wm*64 + mi*16 + quad*4;
#pragma unroll
        for (int ni = 0; ni < 4; ni++) {
            int n = bn0 + wn*64 + ni*16 + l16;
            if (n < N) {
#pragma unroll
                for (int r = 0; r < 4; r++) {
                    size_t idx = (size_t)(mbase + r)*N + n;
                    float v = acc[mi][ni][r];
                    if constexpr (EPI == 0) {
                        ((__bf16*)Cout)[idx] = (__bf16)v;
                    } else if constexpr (EPI == 2) {
                        v += bias[n] + resid[idx];
                        ((float*)Cout)[idx] = v;
                    } else if constexpr (EPI == 3) {
                        v += bias[n];
                        // gelu(tanh) = v*sigmoid(1.5957691216*(v+0.044715 v^3))
                        float u = 1.5957691216057308f*(v + 0.044715f*v*v*v);
                        float g = v * __builtin_amdgcn_rcpf(1.f + __expf(-u));
                        ((__bf16*)Cout)[idx] = (__bf16)g;
                    } else if constexpr (EPI == 4) {
                        v += bias[n] + resid[idx];
                        ((float*)Cout)[idx] = v;
                    }
                }
            }
        }
    }
}

// ---------------- depthwise causal conv (K=4) + SiLU ----------------
// R13: R12's x8 version was transaction-bound (128us, HBM 10%, VALU 9.5%):
// cw[(c0+j)*4+k] scalar loads = 64-line scatter-gather per instr (32/thread),
// and each proj row fetched 4x (FETCH 68.8MB = 2x ideal). Fix:
//  (a) per-thread weights are 32 CONSECUTIVE floats -> 8x float4, static idx.
//  (b) each thread computes 4 consecutive timesteps: 7 proj-row loads for
//      4 outputs (1.75 loads/row vs 4). k-ascending per-output accumulation
//      order preserved -> bit-identical.
__global__ __launch_bounds__(256) void conv_kernel(
    const __bf16* __restrict__ proj, const float* __restrict__ cw,
    const float* __restrict__ cb, __bf16* __restrict__ u_out,
    float* __restrict__ bc_out)
{
    const int NG = CONVD/8;                     // 260 channel groups
    int idx = blockIdx.x*256 + threadIdx.x;     // B_*(L_/4)*NG total
    if (idx >= B_*(L_/4)*NG) return;
    int g  = idx % NG;
    int tg = idx / NG;                          // global 4-row group
    int b  = tg / (L_/4);
    int t0 = (tg % (L_/4)) * 4;
    int c0 = g*8;
    size_t row0 = (size_t)b*L_ + t0;

    // weights: cw[(c0+j)*4+k] spans [c0*4, c0*4+32) -> 8x float4, w4[j][k]
    float4 w4[8];
#pragma unroll
    for (int q = 0; q < 8; q++)
        w4[q] = *(const float4*)&cw[c0*K_ + q*4];
    float4 cb0 = *(const float4*)&cb[c0];
    float4 cb1 = *(const float4*)&cb[c0 + 4];
    float cbv[8] = {cb0.x, cb0.y, cb0.z, cb0.w, cb1.x, cb1.y, cb1.z, cb1.w};

    // 7 input rows: t0-3 .. t0+3 (local i = 0..6, r = t0+i-3)
    float pv[7][8];
#pragma unroll
    for (int i = 0; i < 7; i++) {
        int r = t0 + i - 3;
        if (r >= 0) {
            bf16_8 v = *(const bf16_8*)&proj[((size_t)b*L_ + r)*DPROJ + DIN + c0];
#pragma unroll
            for (int j = 0; j < 8; j++) pv[i][j] = (float)v[j];
        } else {
#pragma unroll
            for (int j = 0; j < 8; j++) pv[i][j] = 0.f;
        }
    }

    // 4 outputs: t = t0+i (i=0..3), tap k uses input local row i+k
#pragma unroll
    for (int i = 0; i < 4; i++) {
        float s[8];
#pragma unroll
        for (int j = 0; j < 8; j++) {
            float acc = cbv[j];
#pragma unroll
            for (int k = 0; k < K_; k++)
                acc += pv[i + k][j] * w4[j][k];
            s[j] = acc / (1.f + __expf(-acc));
        }
        size_t row = row0 + i;
        if (c0 < DIN) {
            bf16_8 o;
#pragma unroll
            for (int j = 0; j < 8; j++) o[j] = (__bf16)s[j];
            *(bf16_8*)&u_out[row*DIN + c0] = o;
        } else {
            int cc = c0 - DIN;                  // 0, 8, 16, 24
            float4 f0 = {s[0], s[1], s[2], s[3]};
            float4 f1 = {s[4], s[5], s[6], s[7]};
            *(float4*)&bc_out[row*32 + cc]     = f0;
            *(float4*)&bc_out[row*32 + cc + 4] = f1;
        }
    }
}

// ---------------- B/C normalize + softplus(dt) ----------------
__global__ __launch_bounds__(64) void prep_kernel(
    const float* __restrict__ bc, const __bf16* __restrict__ proj,
    const float* __restrict__ dt_bias,
    float* __restrict__ Bn, float* __restrict__ Cn, float* __restrict__ dtv)
{
    int row = blockIdx.x;
    int tid = threadIdx.x;
    if (tid < 32) {
        float v = bc[(size_t)row*32 + tid];
        float ss = v*v;
        ss += __shfl_xor(ss, 1, 16);
        ss += __shfl_xor(ss, 2, 16);
        ss += __shfl_xor(ss, 4, 16);
        ss += __shfl_xor(ss, 8, 16);
        float nv = v * rsqrtf(ss + 1e-6f);
        if (tid < 16) Bn[(size_t)row*16 + tid] = nv;
        else Cn[(size_t)row*16 + (tid-16)] = nv;
    } else {
        int h = tid - 32;
        float xv = (float)proj[(size_t)row*DPROJ + 2*DIN + 2*N_ + h] + dt_bias[h];
        float sp = (xv > 20.f) ? xv : log1pf(__expf(xv));
        dtv[(size_t)row*32 + h] = sp;
    }
}

// ================= chunked parallel scan =================
__global__ __launch_bounds__(64) void scan_phase0(
    const float* __restrict__ dtv, const float* __restrict__ A_param,
    float* __restrict__ Mprod)
{
    int blk = blockIdx.x;
    int cg = blk & 15;
    int h  = (blk >> 4) & 31;
    int b  = blk >> 9;
    int lane = threadIdx.x;
    int n  = lane & 15;
    int c  = cg*4 + (lane >> 4);
    int bh = b*32 + h;

    float Av = fmaxf(A_param[h*16 + n], 0.f);
    float P00 = 1.f, P01 = 0.f, P10 = 0.f, P11 = 1.f;
    size_t r0 = (size_t)b*L_ + (size_t)c*CH;

#pragma unroll 4
    for (int tt = 0; tt < CH; tt++) {
        float d  = dtv[(r0 + tt)*32 + h];
        float rc = __builtin_amdgcn_rcpf(fmaf(d*d, Av, 1.f));
        float da = d*Av;
        float n00 = rc*fmaf(-da, P10, P00);
        float n01 = rc*fmaf(-da, P11, P01);
        float n10 = rc*fmaf(d, P00, P10);
        float n11 = rc*fmaf(d, P01, P11);
        P00=n00; P01=n01; P10=n10; P11=n11;
    }

    size_t mi = (((size_t)bh*NC + c)*16 + n)*4;
    Mprod[mi+0]=P00; Mprod[mi+1]=P01; Mprod[mi+2]=P10; Mprod[mi+3]=P11;
}

// R10 form (LDS rc/d tables) + R11 unroll 8; single full-grid dispatch
__global__ __launch_bounds__(64) void scan_phase1(
    const float* __restrict__ dtv, const float* __restrict__ Bn,
    const __bf16* __restrict__ u, const float* __restrict__ A_param,
    float* __restrict__ vbuf)
{
    __shared__ float rcT[CH][16];   // 4 KB
    __shared__ float dT[CH];        // 256 B
    int blk = blockIdx.x;
    int c  = blk & (NC-1);
    int pg = (blk >> 6) & 3;
    int h  = (blk >> 8) & 31;
    int b  = blk >> 13;
    int lane = threadIdx.x;
    int pl = lane >> 2, nq = lane & 3;
    int p = pg*16 + pl;
    int ch = h*64 + p;
    int bh = b*32 + h;

    size_t r0 = (size_t)b*L_ + (size_t)c*CH;

    // table build: lane tt computes rc for its timestep (bit-identical ops)
    {
        float d = dtv[(r0 + lane)*32 + h];
        dT[lane] = d;
        float dd = d*d;
#pragma unroll
        for (int n = 0; n < 16; n++) {
            float Avn = fmaxf(A_param[h*16 + n], 0.f);
            rcT[lane][n] = __builtin_amdgcn_rcpf(fmaf(dd, Avn, 1.f));
        }
    }
    __syncthreads();

    float Av[4];
#pragma unroll
    for (int j = 0; j < 4; j++) Av[j] = fmaxf(A_param[h*16 + nq*4 + j], 0.f);

    float z[4] = {}, y[4] = {};

#pragma unroll 8
    for (int tt = 0; tt < CH; tt++) {
        size_t rn = r0 + tt;
        float d  = dT[tt];
        float4 rc4 = *(const float4*)&rcT[tt][nq*4];
        float4 Bv = *(const float4*)&Bn[rn*16 + nq*4];
        float up = (float)u[rn*DIN + ch];
        float rcj[4] = {rc4.x, rc4.y, rc4.z, rc4.w};
        float Bvj[4] = {Bv.x, Bv.y, Bv.z, Bv.w};
#pragma unroll
        for (int j = 0; j < 4; j++) {
            float q = fmaf(-Av[j], y[j], up*Bvj[j]);
            float zn = fmaf(d, q, z[j]) * rcj[j];
            z[j] = zn;
            y[j] = fmaf(d, zn, y[j]);
        }
    }

    size_t vb = ((size_t)bh*NC + c)*16;
#pragma unroll
    for (int j = 0; j < 4; j++) {
        int n = nq*4 + j;
        size_t vi = ((vb + n)*64 + p)*2;
        vbuf[vi]   = z[j];
        vbuf[vi+1] = y[j];
    }
}

// n-parallel phase2 (R11): 1024 blocks, one (bh,n) chain each; bit-identical.
__global__ __launch_bounds__(64) void scan_phase2(
    float* __restrict__ vbuf, const float* __restrict__ Mprod)
{
    int blk = blockIdx.x;
    int bh = blk >> 4;
    int n  = blk & 15;
    int p = threadIdx.x;
    float z = 0.f, y = 0.f;
#pragma unroll 4
    for (int c = 0; c < NC; c++) {
        size_t base = ((size_t)bh*NC + c)*16 + n;
        float4 mm = *(const float4*)&Mprod[base*4];
        size_t vi = (base*64 + p)*2;
        float vz = vbuf[vi], vy = vbuf[vi+1];
        vbuf[vi]   = z;
        vbuf[vi+1] = y;
        float zn = mm.x*z + mm.y*y + vz;
        float yn = mm.z*z + mm.w*y + vy;
        z = zn; y = yn;
    }
}

__global__ __launch_bounds__(64) void scan_phase3(
    const float* __restrict__ dtv, const float* __restrict__ Bn,
    const float* __restrict__ Cn, const __bf16* __restrict__ u,
    const __bf16* __restrict__ proj, const float* __restrict__ A_param,
    const float* __restrict__ D_skip, const float* __restrict__ vbuf,
    __bf16* __restrict__ y2)
{
    __shared__ float rcT[CH][16];   // 4 KB
    __shared__ float dT[CH];        // 256 B
    int blk = blockIdx.x;
    int c  = blk & (NC-1);
    int pg = (blk >> 6) & 3;
    int h  = (blk >> 8) & 31;
    int b  = blk >> 13;
    int lane = threadIdx.x;
    int pl = lane >> 2, nq = lane & 3;
    int p = pg*16 + pl;
    int ch = h*64 + p;
    int bh = b*32 + h;

    size_t r0 = (size_t)b*L_ + (size_t)c*CH;

    // table build (bit-identical rc)
    {
        float d = dtv[(r0 + lane)*32 + h];
        dT[lane] = d;
        float dd = d*d;
#pragma unroll
        for (int n = 0; n < 16; n++) {
            float Avn = fmaxf(A_param[h*16 + n], 0.f);
            rcT[lane][n] = __builtin_amdgcn_rcpf(fmaf(dd, Avn, 1.f));
        }
    }
    __syncthreads();

    float Av[4];
#pragma unroll
    for (int j = 0; j < 4; j++) Av[j] = fmaxf(A_param[h*16 + nq*4 + j], 0.f);
    float Dsk = D_skip[h];

    float z[4], y[4];
    size_t vb = ((size_t)bh*NC + c)*16;
#pragma unroll
    for (int j = 0; j < 4; j++) {
        int n = nq*4 + j;
        size_t vi = ((vb + n)*64 + p)*2;
        z[j] = vbuf[vi];
        y[j] = vbuf[vi+1];
    }

#pragma unroll 8
    for (int tt = 0; tt < CH; tt++) {
        size_t rn = r0 + tt;
        float d  = dT[tt];
        float4 rc4 = *(const float4*)&rcT[tt][nq*4];
        float4 Bv = *(const float4*)&Bn[rn*16 + nq*4];
        float4 Cv = *(const float4*)&Cn[rn*16 + nq*4];
        float up = (float)u[rn*DIN + ch];
        float zg = (float)proj[rn*DPROJ + ch];
        float rcj[4] = {rc4.x, rc4.y, rc4.z, rc4.w};
        float Bvj[4] = {Bv.x, Bv.y, Bv.z, Bv.w};
        float Cvj[4] = {Cv.x, Cv.y, Cv.z, Cv.w};
        float s = 0.f;
#pragma unroll
        for (int j = 0; j < 4; j++) {
            float q = fmaf(-Av[j], y[j], up*Bvj[j]);
            float zn = fmaf(d, q, z[j]) * rcj[j];
            z[j] = zn;
            y[j] = fmaf(d, zn, y[j]);
            s = fmaf(y[j], Cvj[j], s);
        }
        s += __shfl_xor(s, 1, 64);
        s += __shfl_xor(s, 2, 64);
        if (nq == 0) {
            float sig = __builtin_amdgcn_rcpf(1.f + __expf(-zg));
            y2[rn*DIN + ch] = (__bf16)((s + Dsk*up) * (zg * sig));
        }
    }
}

extern "C" void kernel_launch(void* const* d_in, const int* in_sizes, int n_in,
                              void* d_out, int out_size, void* d_ws, size_t ws_size,
                              hipStream_t stream) {
    const float* x         = (const float*)d_in[0];
    const float* norm1_w   = (const float*)d_in[1];
    const float* in_proj_w = (const float*)d_in[2];
    const float* conv_w    = (const float*)d_in[3];
    const float* conv_b    = (const float*)d_in[4];
    const float* A_param   = (const float*)d_in[5];
    const float* dt_bias   = (const float*)d_in[6];
    const float* D_skip    = (const float*)d_in[7];
    const float* out_proj_w= (const float*)d_in[8];
    const float* out_proj_b= (const float*)d_in[9];
    const float* norm2_w   = (const float*)d_in[10];
    const float* fc1_w     = (const float*)d_in[11];
    const float* fc1_b     = (const float*)d_in[12];
    const float* fc2_w     = (const float*)d_in[13];
    const float* fc2_b     = (const float*)d_in[14];
    float* out = (float*)d_out;

    // -------- workspace layout with lifetime-based aliasing (~148 MB) --------
    char* ws = (char*)d_ws;
    const size_t R0 = 0;
    const size_t R0_SZ = (size_t)M_ROWS*DPROJ*2;               // 68,157,440
    const size_t R1 = R0_SZ;
    const size_t R1_SZ = (size_t)M_ROWS*4*D_*2;                 // 67,108,864
    const size_t R2 = R1 + R1_SZ;                               // 135,266,304

    __bf16* proj   = (__bf16*)(ws + R0);
    float*  x2     = (float*) (ws + R0);                        // aliases proj (dead)
    __bf16* x2n    = (__bf16*)(ws + R0 + (size_t)M_ROWS*D_*4);
    __bf16* xn     = (__bf16*)(ws + R1);
    __bf16* y2     = (__bf16*)(ws + R1);                        // aliases xn (dead)
    __bf16* u_conv = (__bf16*)(ws + R1 + (size_t)M_ROWS*DIN*2);
    __bf16* h1     = (__bf16*)(ws + R1);                        // aliases y2+u_conv (dead)
    float*  bcraw  = (float*)(ws + R2);                                       // 1 MB
    float*  Bn     = (float*)(ws + R2 + (size_t)M_ROWS*32*4);                 // 0.5 MB
    float*  Cn     = (float*)(ws + R2 + (size_t)M_ROWS*32*4 + (size_t)M_ROWS*16*4);
    float*  dtv    = (float*)(ws + R2 + (size_t)M_ROWS*32*4 + (size_t)M_ROWS*16*4*2);
    float*  Mprod  = (float*)(ws + R2 + (size_t)M_ROWS*32*4*2 + (size_t)M_ROWS*16*4*2); // 1 MB
    __bf16* Wb     = (__bf16*)(ws + R2 + (size_t)M_ROWS*32*4*2 + (size_t)M_ROWS*16*4*2
                                 + (size_t)64*64*16*4*4);       // 8.52 MB slot, reused per GEMM

    float* vbuf = (float*)d_out;   // scan scratch; fully overwritten by fc2 GEMM

    // 1. RMSNorm1 (fp32 x -> bf16 xn)
    rms_kernel<float><<<M_ROWS, 256, 0, stream>>>(x, norm1_w, xn);

    // 2. in_proj GEMM: proj = xn @ in_proj_w^T
    {
        int n = DPROJ*D_;
        cvt_kernel<<<(n/8 + 255)/256, 256, 0, stream>>>(in_proj_w, Wb, n);
        dim3 grid((DPROJ + BN - 1)/BN, M_ROWS/BM);
        gemm_kernel<0><<<grid, 256, 0, stream>>>(xn, Wb, proj, nullptr, nullptr,
                                                 M_ROWS, DPROJ, D_);
    }

    // 3. conv + silu (4-row x 8-channel per thread)
    {
        int total = B_*(L_/4)*(CONVD/8);   // 532,480
        conv_kernel<<<(total + 255)/256, 256, 0, stream>>>(proj, conv_w, conv_b, u_conv, bcraw);
    }

    // 4. B/C normalize + dt softplus
    prep_kernel<<<M_ROWS, 64, 0, stream>>>(bcraw, proj, dt_bias, Bn, Cn, dtv);

    // 5. chunked scan
    {
        int full = B_*H_*4*NC;   // 16384
        scan_phase0<<<B_*H_*16, 64, 0, stream>>>(dtv, A_param, Mprod);
        scan_phase1<<<full, 64, 0, stream>>>(dtv, Bn, u_conv, A_param, vbuf);
        scan_phase2<<<B_*H_*16, 64, 0, stream>>>(vbuf, Mprod);
        scan_phase3<<<full, 64, 0, stream>>>(dtv, Bn, Cn, u_conv, proj, A_param, D_skip,
                                             vbuf, y2);
    }

    // 6. out_proj GEMM + bias + residual(x) -> x2 (fp32, overwrites dead proj)
    {
        int n = D_*DIN;
        cvt_kernel<<<(n/8 + 255)/256, 256, 0, stream>>>(out_proj_w, Wb, n);
        dim3 grid((D_ + BN - 1)/BN, M_ROWS/BM);
        gemm_kernel<2><<<grid, 256, 0, stream>>>(y2, Wb, x2, out_proj_b, x, M_ROWS, D_, DIN);
    }

    // 7. RMSNorm2
    rms_kernel<float><<<M_ROWS, 256, 0, stream>>>(x2, norm2_w, x2n);

    // 8. fc1 GEMM + bias + gelu -> h1 (overwrites dead y2/u_conv)
    {
        int n = 4*D_*D_;
        cvt_kernel<<<(n/8 + 255)/256, 256, 0, stream>>>(fc1_w, Wb, n);
        dim3 grid((4*D_ + BN - 1)/BN, M_ROWS/BM);
        gemm_kernel<3><<<grid, 256, 0, stream>>>(x2n, Wb, h1, fc1_b, nullptr, M_ROWS, 4*D_, D_);
    }

    // 9. fc2 GEMM + bias + residual(x2) -> out (fp32)
    {
        int n = D_*4*D_;
        cvt_kernel<<<(n/8 + 255)/256, 256, 0, stream>>>(fc2_w, Wb, n);
        dim3 grid((D_ + BN - 1)/BN, M_ROWS/BM);
        gemm_kernel<4><<<grid, 256, 0, stream>>>(h1, Wb, out, fc2_b, x2, M_ROWS, D_, 4*D_);
    }
}

// Round 14
// 626.097 us; speedup vs baseline: 1.2353x; 1.1134x over previous
//
#include <hip/hip_runtime.h>
#include <hip/hip_bf16.h>
#include <math.h>

#define B_ 2
#define L_ 4096
#define D_ 1024
#define DIN 2048
#define DPROJ 4160
#define CONVD 2080
#define H_ 32
#define P_ 64
#define N_ 16
#define K_ 4
#define M_ROWS (B_*L_)

// chunked scan: NC chunks of CH steps
#define NC 64
#define CH 64
#define TP 20   // padded LDS table row (floats): 16B-aligned float4 reads,
                // build writes spread across granule groups (8-way, amortized)

typedef __bf16 bf16_8 __attribute__((ext_vector_type(8)));
typedef float f32x4 __attribute__((ext_vector_type(4)));

// async global->LDS, 16 B per lane; LDS dest = wave-uniform base + lane*16
__device__ __forceinline__ void gload_lds16(const void* g, void* l) {
    __builtin_amdgcn_global_load_lds(
        (const __attribute__((address_space(1))) unsigned int*)g,
        (__attribute__((address_space(3))) unsigned int*)l, 16, 0, 0);
}

// ---------------- fp32 -> bf16 weight conversion ----------------
__global__ __launch_bounds__(256) void cvt_kernel(const float* __restrict__ src,
        __bf16* __restrict__ dst, int n) {
    int i = (blockIdx.x*256 + threadIdx.x)*8;
    if (i < n) {
        float4 f0 = *(const float4*)(src + i);
        float4 f1 = *(const float4*)(src + i + 4);
        bf16_8 o;
        o[0]=(__bf16)f0.x; o[1]=(__bf16)f0.y; o[2]=(__bf16)f0.z; o[3]=(__bf16)f0.w;
        o[4]=(__bf16)f1.x; o[5]=(__bf16)f1.y; o[6]=(__bf16)f1.z; o[7]=(__bf16)f1.w;
        *(bf16_8*)(dst + i) = o;
    }
}

// ---------------- RMSNorm (in fp32, out bf16) ----------------
template<typename TI>
__global__ __launch_bounds__(256) void rms_kernel(const TI* __restrict__ x,
        const float* __restrict__ w, __bf16* __restrict__ out) {
    int row = blockIdx.x;
    int tid = threadIdx.x;
    const TI* xr = x + (size_t)row * D_;
    float v[4];
    float ss = 0.f;
#pragma unroll
    for (int i = 0; i < 4; i++) {
        v[i] = (float)xr[tid*4 + i];
        ss += v[i]*v[i];
    }
#pragma unroll
    for (int off = 32; off >= 1; off >>= 1) ss += __shfl_xor(ss, off, 64);
    __shared__ float sred[4];
    int wave = tid >> 6;
    if ((tid & 63) == 0) sred[wave] = ss;
    __syncthreads();
    ss = sred[0] + sred[1] + sred[2] + sred[3];
    float scale = rsqrtf(ss * (1.f/(float)D_) + 1e-6f);
#pragma unroll
    for (int i = 0; i < 4; i++)
        out[(size_t)row*D_ + tid*4 + i] = (__bf16)(v[i] * scale * w[tid*4 + i]);
}

// ---------------- GEMM (128x128, BK=64 as 2x32 sub-blocks): C = A @ W^T --------
// R9 verdict: BK=128 regressed — BK=64 is this structure's optimum (R6).
// EPI 0: bf16 | EPI 2/4: +bias+resid -> fp32 | EPI 3: +bias, gelu -> bf16
#define BM 128
#define BN 128
#define BK 64

template<int EPI>
__global__ __launch_bounds__(256) void gemm_kernel(
    const __bf16* __restrict__ A, const __bf16* __restrict__ W,
    void* __restrict__ Cout, const float* __restrict__ bias,
    const float* __restrict__ resid, int M, int N, int K)
{
    __shared__ __attribute__((aligned(16))) __bf16 As[2][BM][32];   // 16 KB
    __shared__ __attribute__((aligned(16))) __bf16 Bs[2][BN][32];   // 16 KB
    int tid = threadIdx.x;
    int lane = tid & 63, wave = tid >> 6;
    int wm = wave >> 1, wn = wave & 1;
    int quad = lane >> 4, l16 = lane & 15;

    // grouped raster: groups of 8 M-blocks share the N-sweep
    int num_n = gridDim.x, num_m = gridDim.y;
    int pid = blockIdx.y * num_n + blockIdx.x;
    const int G = 8;
    int gsz = G * num_n;
    int grp = pid / gsz;
    int rem = pid - grp * gsz;
    int first_m = grp * G;
    int gm = (num_m - first_m < G) ? (num_m - first_m) : G;
    int m_idx = first_m + rem % gm;
    int n_idx = rem / gm;
    int bm0 = m_idx * BM, bn0 = n_idx * BN;

    int srow = lane >> 2;   // 0..15 row within 16-row chunk
    int sseg = lane & 3;    // 16 B (8 bf16) segment within 32-col sub-row

    f32x4 acc[4][4] = {};

    for (int kk = 0; kk < K; kk += BK) {
#pragma unroll
        for (int kh = 0; kh < 2; kh++) {
#pragma unroll
            for (int k = 0; k < 2; k++) {
                int c = wave*2 + k;                 // chunk 0..7 (16 rows each)
                int arow = bm0 + c*16 + srow;
                gload_lds16(A + (size_t)arow*K + kk + kh*32 + sseg*8,
                            (char*)&As[kh][0][0] + c*1024);
                int nr = bn0 + c*16 + srow;
                if (nr < N)
                    gload_lds16(W + (size_t)nr*K + kk + kh*32 + sseg*8,
                                (char*)&Bs[kh][0][0] + c*1024);
            }
        }
        __syncthreads();
#pragma unroll
        for (int kh = 0; kh < 2; kh++) {
            bf16_8 af[4], bfr[4];
#pragma unroll
            for (int i = 0; i < 4; i++) {
                af[i]  = *(const bf16_8*)&As[kh][wm*64 + i*16 + l16][quad*8];
                bfr[i] = *(const bf16_8*)&Bs[kh][wn*64 + i*16 + l16][quad*8];
            }
#pragma unroll
            for (int mi = 0; mi < 4; mi++)
#pragma unroll
                for (int ni = 0; ni < 4; ni++)
                    acc[mi][ni] = __builtin_amdgcn_mfma_f32_16x16x32_bf16(af[mi], bfr[ni], acc[mi][ni], 0, 0, 0);
        }
        __syncthreads();
    }

#pragma unroll
    for (int mi = 0; mi < 4; mi++) {
        int mbase = bm0 + wm*64 + mi*16 + quad*4;
#pragma unroll
        for (int ni = 0; ni < 4; ni++) {
            int n = bn0 + wn*64 + ni*16 + l16;
            if (n < N) {
#pragma unroll
                for (int r = 0; r < 4; r++) {
                    size_t idx = (size_t)(mbase + r)*N + n;
                    float v = acc[mi][ni][r];
                    if constexpr (EPI == 0) {
                        ((__bf16*)Cout)[idx] = (__bf16)v;
                    } else if constexpr (EPI == 2) {
                        v += bias[n] + resid[idx];
                        ((float*)Cout)[idx] = v;
                    } else if constexpr (EPI == 3) {
                        v += bias[n];
                        // gelu(tanh) = v*sigmoid(1.5957691216*(v+0.044715 v^3))
                        float u = 1.5957691216057308f*(v + 0.044715f*v*v*v);
                        float g = v * __builtin_amdgcn_rcpf(1.f + __expf(-u));
                        ((__bf16*)Cout)[idx] = (__bf16)g;
                    } else if constexpr (EPI == 4) {
                        v += bias[n] + resid[idx];
                        ((float*)Cout)[idx] = v;
                    }
                }
            }
        }
    }
}

// ---------------- depthwise causal conv (K=4) + SiLU (R13 form) ----------------
__global__ __launch_bounds__(256) void conv_kernel(
    const __bf16* __restrict__ proj, const float* __restrict__ cw,
    const float* __restrict__ cb, __bf16* __restrict__ u_out,
    float* __restrict__ bc_out)
{
    const int NG = CONVD/8;                     // 260 channel groups
    int idx = blockIdx.x*256 + threadIdx.x;     // B_*(L_/4)*NG total
    if (idx >= B_*(L_/4)*NG) return;
    int g  = idx % NG;
    int tg = idx / NG;                          // global 4-row group
    int b  = tg / (L_/4);
    int t0 = (tg % (L_/4)) * 4;
    int c0 = g*8;
    size_t row0 = (size_t)b*L_ + t0;

    float4 w4[8];
#pragma unroll
    for (int q = 0; q < 8; q++)
        w4[q] = *(const float4*)&cw[c0*K_ + q*4];
    float4 cb0 = *(const float4*)&cb[c0];
    float4 cb1 = *(const float4*)&cb[c0 + 4];
    float cbv[8] = {cb0.x, cb0.y, cb0.z, cb0.w, cb1.x, cb1.y, cb1.z, cb1.w};

    float pv[7][8];
#pragma unroll
    for (int i = 0; i < 7; i++) {
        int r = t0 + i - 3;
        if (r >= 0) {
            bf16_8 v = *(const bf16_8*)&proj[((size_t)b*L_ + r)*DPROJ + DIN + c0];
#pragma unroll
            for (int j = 0; j < 8; j++) pv[i][j] = (float)v[j];
        } else {
#pragma unroll
            for (int j = 0; j < 8; j++) pv[i][j] = 0.f;
        }
    }

#pragma unroll
    for (int i = 0; i < 4; i++) {
        float s[8];
#pragma unroll
        for (int j = 0; j < 8; j++) {
            float acc = cbv[j];
#pragma unroll
            for (int k = 0; k < K_; k++)
                acc += pv[i + k][j] * w4[j][k];
            s[j] = acc / (1.f + __expf(-acc));
        }
        size_t row = row0 + i;
        if (c0 < DIN) {
            bf16_8 o;
#pragma unroll
            for (int j = 0; j < 8; j++) o[j] = (__bf16)s[j];
            *(bf16_8*)&u_out[row*DIN + c0] = o;
        } else {
            int cc = c0 - DIN;
            float4 f0 = {s[0], s[1], s[2], s[3]};
            float4 f1 = {s[4], s[5], s[6], s[7]};
            *(float4*)&bc_out[row*32 + cc]     = f0;
            *(float4*)&bc_out[row*32 + cc + 4] = f1;
        }
    }
}

// ---------------- B/C normalize + softplus(dt) ----------------
__global__ __launch_bounds__(64) void prep_kernel(
    const float* __restrict__ bc, const __bf16* __restrict__ proj,
    const float* __restrict__ dt_bias,
    float* __restrict__ Bn, float* __restrict__ Cn, float* __restrict__ dtv)
{
    int row = blockIdx.x;
    int tid = threadIdx.x;
    if (tid < 32) {
        float v = bc[(size_t)row*32 + tid];
        float ss = v*v;
        ss += __shfl_xor(ss, 1, 16);
        ss += __shfl_xor(ss, 2, 16);
        ss += __shfl_xor(ss, 4, 16);
        ss += __shfl_xor(ss, 8, 16);
        float nv = v * rsqrtf(ss + 1e-6f);
        if (tid < 16) Bn[(size_t)row*16 + tid] = nv;
        else Cn[(size_t)row*16 + (tid-16)] = nv;
    } else {
        int h = tid - 32;
        float xv = (float)proj[(size_t)row*DPROJ + 2*DIN + 2*N_ + h] + dt_bias[h];
        float sp = (xv > 20.f) ? xv : log1pf(__expf(xv));
        dtv[(size_t)row*32 + h] = sp;
    }
}

// ================= chunked parallel scan =================
__global__ __launch_bounds__(64) void scan_phase0(
    const float* __restrict__ dtv, const float* __restrict__ A_param,
    float* __restrict__ Mprod)
{
    int blk = blockIdx.x;
    int cg = blk & 15;
    int h  = (blk >> 4) & 31;
    int b  = blk >> 9;
    int lane = threadIdx.x;
    int n  = lane & 15;
    int c  = cg*4 + (lane >> 4);
    int bh = b*32 + h;

    float Av = fmaxf(A_param[h*16 + n], 0.f);
    float P00 = 1.f, P01 = 0.f, P10 = 0.f, P11 = 1.f;
    size_t r0 = (size_t)b*L_ + (size_t)c*CH;

#pragma unroll 4
    for (int tt = 0; tt < CH; tt++) {
        float d  = dtv[(r0 + tt)*32 + h];
        float rc = __builtin_amdgcn_rcpf(fmaf(d*d, Av, 1.f));
        float da = d*Av;
        float n00 = rc*fmaf(-da, P10, P00);
        float n01 = rc*fmaf(-da, P11, P01);
        float n10 = rc*fmaf(d, P00, P10);
        float n11 = rc*fmaf(d, P01, P11);
        P00=n00; P01=n01; P10=n10; P11=n11;
    }

    size_t mi = (((size_t)bh*NC + c)*16 + n)*4;
    Mprod[mi+0]=P00; Mprod[mi+1]=P01; Mprod[mi+2]=P10; Mprod[mi+3]=P11;
}

// R14: lane-owns-all-16-n layout. Block = (b,h,chunk), 64 lanes = 64 p.
// Removes the 4x per-t scalar replication, 2 shfl/t, divergent epilogue of
// the old 4-lane-per-p layout (82 VALU inst/t measured -> ~30). Per-t
// B/C/rc/d are lane-uniform -> LDS tables, uniform-address broadcast reads
// (conflict-free). z/y per-n op sequence unchanged -> vbuf bit-identical;
// s-summation order changes (sequential-16) -> fp32 noise only.
__global__ __launch_bounds__(64) void scan_phase1(
    const float* __restrict__ dtv, const float* __restrict__ Bn,
    const __bf16* __restrict__ u, const float* __restrict__ A_param,
    float* __restrict__ vbuf)
{
    __shared__ float rcT[CH][TP];   // 5 KB
    __shared__ float BT[CH][TP];    // 5 KB
    __shared__ float dT[CH];        // 256 B
    int blk = blockIdx.x;
    int c  = blk & (NC-1);
    int h  = (blk >> 6) & 31;
    int b  = blk >> 11;
    int lane = threadIdx.x;         // = p
    int ch = h*64 + lane;
    int bh = b*32 + h;

    size_t r0 = (size_t)b*L_ + (size_t)c*CH;

    // Av[16] (fmax applied, same op as before)
    float Av[16];
#pragma unroll
    for (int g = 0; g < 4; g++) {
        float4 a4 = *(const float4*)&A_param[h*16 + g*4];
        Av[g*4+0] = fmaxf(a4.x, 0.f); Av[g*4+1] = fmaxf(a4.y, 0.f);
        Av[g*4+2] = fmaxf(a4.z, 0.f); Av[g*4+3] = fmaxf(a4.w, 0.f);
    }

    // table build: lane tt stages d, B-row, rc-row for its timestep
    {
        int tt = lane;
        size_t rn = r0 + tt;
        float d = dtv[rn*32 + h];
        dT[tt] = d;
        float dd = d*d;
#pragma unroll
        for (int g = 0; g < 4; g++) {
            float4 b4 = *(const float4*)&Bn[rn*16 + g*4];
            *(float4*)&BT[tt][g*4] = b4;
            float4 r4;
            r4.x = __builtin_amdgcn_rcpf(fmaf(dd, Av[g*4+0], 1.f));
            r4.y = __builtin_amdgcn_rcpf(fmaf(dd, Av[g*4+1], 1.f));
            r4.z = __builtin_amdgcn_rcpf(fmaf(dd, Av[g*4+2], 1.f));
            r4.w = __builtin_amdgcn_rcpf(fmaf(dd, Av[g*4+3], 1.f));
            *(float4*)&rcT[tt][g*4] = r4;
        }
    }
    __syncthreads();

    float z[16] = {}, y[16] = {};

#pragma unroll 4
    for (int tt = 0; tt < CH; tt++) {
        size_t rn = r0 + tt;
        float d  = dT[tt];
        float up = (float)u[rn*DIN + ch];
#pragma unroll
        for (int g = 0; g < 4; g++) {
            float4 B4  = *(const float4*)&BT[tt][g*4];
            float4 rc4 = *(const float4*)&rcT[tt][g*4];
            float Bj[4]  = {B4.x, B4.y, B4.z, B4.w};
            float rcj[4] = {rc4.x, rc4.y, rc4.z, rc4.w};
#pragma unroll
            for (int j = 0; j < 4; j++) {
                int n = g*4 + j;
                float q = fmaf(-Av[n], y[n], up*Bj[j]);
                float zn = fmaf(d, q, z[n]) * rcj[j];
                z[n] = zn;
                y[n] = fmaf(d, zn, y[n]);
            }
        }
    }

    size_t vb = ((size_t)bh*NC + c)*16;
#pragma unroll
    for (int n = 0; n < 16; n++) {
        size_t vi = ((vb + n)*64 + lane)*2;
        vbuf[vi]   = z[n];
        vbuf[vi+1] = y[n];
    }
}

// n-parallel phase2 (R11): 1024 blocks, one (bh,n) chain each; bit-identical.
__global__ __launch_bounds__(64) void scan_phase2(
    float* __restrict__ vbuf, const float* __restrict__ Mprod)
{
    int blk = blockIdx.x;
    int bh = blk >> 4;
    int n  = blk & 15;
    int p = threadIdx.x;
    float z = 0.f, y = 0.f;
#pragma unroll 4
    for (int c = 0; c < NC; c++) {
        size_t base = ((size_t)bh*NC + c)*16 + n;
        float4 mm = *(const float4*)&Mprod[base*4];
        size_t vi = (base*64 + p)*2;
        float vz = vbuf[vi], vy = vbuf[vi+1];
        vbuf[vi]   = z;
        vbuf[vi+1] = y;
        float zn = mm.x*z + mm.y*y + vz;
        float yn = mm.z*z + mm.w*y + vy;
        z = zn; y = yn;
    }
}

__global__ __launch_bounds__(64) void scan_phase3(
    const float* __restrict__ dtv, const float* __restrict__ Bn,
    const float* __restrict__ Cn, const __bf16* __restrict__ u,
    const __bf16* __restrict__ proj, const float* __restrict__ A_param,
    const float* __restrict__ D_skip, const float* __restrict__ vbuf,
    __bf16* __restrict__ y2)
{
    __shared__ float rcT[CH][TP];   // 5 KB
    __shared__ float BT[CH][TP];    // 5 KB
    __shared__ float CT[CH][TP];    // 5 KB
    __shared__ float dT[CH];        // 256 B
    int blk = blockIdx.x;
    int c  = blk & (NC-1);
    int h  = (blk >> 6) & 31;
    int b  = blk >> 11;
    int lane = threadIdx.x;         // = p
    int ch = h*64 + lane;
    int bh = b*32 + h;

    size_t r0 = (size_t)b*L_ + (size_t)c*CH;

    float Av[16];
#pragma unroll
    for (int g = 0; g < 4; g++) {
        float4 a4 = *(const float4*)&A_param[h*16 + g*4];
        Av[g*4+0] = fmaxf(a4.x, 0.f); Av[g*4+1] = fmaxf(a4.y, 0.f);
        Av[g*4+2] = fmaxf(a4.z, 0.f); Av[g*4+3] = fmaxf(a4.w, 0.f);
    }
    float Dsk = D_skip[h];

    // table build
    {
        int tt = lane;
        size_t rn = r0 + tt;
        float d = dtv[rn*32 + h];
        dT[tt] = d;
        float dd = d*d;
#pragma unroll
        for (int g = 0; g < 4; g++) {
            float4 b4 = *(const float4*)&Bn[rn*16 + g*4];
            float4 c4 = *(const float4*)&Cn[rn*16 + g*4];
            *(float4*)&BT[tt][g*4] = b4;
            *(float4*)&CT[tt][g*4] = c4;
            float4 r4;
            r4.x = __builtin_amdgcn_rcpf(fmaf(dd, Av[g*4+0], 1.f));
            r4.y = __builtin_amdgcn_rcpf(fmaf(dd, Av[g*4+1], 1.f));
            r4.z = __builtin_amdgcn_rcpf(fmaf(dd, Av[g*4+2], 1.f));
            r4.w = __builtin_amdgcn_rcpf(fmaf(dd, Av[g*4+3], 1.f));
            *(float4*)&rcT[tt][g*4] = r4;
        }
    }
    __syncthreads();

    float z[16], y[16];
    size_t vb = ((size_t)bh*NC + c)*16;
#pragma unroll
    for (int n = 0; n < 16; n++) {
        size_t vi = ((vb + n)*64 + lane)*2;
        z[n] = vbuf[vi];
        y[n] = vbuf[vi+1];
    }

#pragma unroll 4
    for (int tt = 0; tt < CH; tt++) {
        size_t rn = r0 + tt;
        float d  = dT[tt];
        float up = (float)u[rn*DIN + ch];
        float zg = (float)proj[rn*DPROJ + ch];
        float s = 0.f;
#pragma unroll
        for (int g = 0; g < 4; g++) {
            float4 B4  = *(const float4*)&BT[tt][g*4];
            float4 C4  = *(const float4*)&CT[tt][g*4];
            float4 rc4 = *(const float4*)&rcT[tt][g*4];
            float Bj[4]  = {B4.x, B4.y, B4.z, B4.w};
            float Cj[4]  = {C4.x, C4.y, C4.z, C4.w};
            float rcj[4] = {rc4.x, rc4.y, rc4.z, rc4.w};
#pragma unroll
            for (int j = 0; j < 4; j++) {
                int n = g*4 + j;
                float q = fmaf(-Av[n], y[n], up*Bj[j]);
                float zn = fmaf(d, q, z[n]) * rcj[j];
                z[n] = zn;
                y[n] = fmaf(d, zn, y[n]);
                s = fmaf(y[n], Cj[j], s);
            }
        }
        float sig = __builtin_amdgcn_rcpf(1.f + __expf(-zg));
        y2[rn*DIN + ch] = (__bf16)((s + Dsk*up) * (zg * sig));
    }
}

extern "C" void kernel_launch(void* const* d_in, const int* in_sizes, int n_in,
                              void* d_out, int out_size, void* d_ws, size_t ws_size,
                              hipStream_t stream) {
    const float* x         = (const float*)d_in[0];
    const float* norm1_w   = (const float*)d_in[1];
    const float* in_proj_w = (const float*)d_in[2];
    const float* conv_w    = (const float*)d_in[3];
    const float* conv_b    = (const float*)d_in[4];
    const float* A_param   = (const float*)d_in[5];
    const float* dt_bias   = (const float*)d_in[6];
    const float* D_skip    = (const float*)d_in[7];
    const float* out_proj_w= (const float*)d_in[8];
    const float* out_proj_b= (const float*)d_in[9];
    const float* norm2_w   = (const float*)d_in[10];
    const float* fc1_w     = (const float*)d_in[11];
    const float* fc1_b     = (const float*)d_in[12];
    const float* fc2_w     = (const float*)d_in[13];
    const float* fc2_b     = (const float*)d_in[14];
    float* out = (float*)d_out;

    // -------- workspace layout with lifetime-based aliasing (~148 MB) --------
    char* ws = (char*)d_ws;
    const size_t R0 = 0;
    const size_t R0_SZ = (size_t)M_ROWS*DPROJ*2;               // 68,157,440
    const size_t R1 = R0_SZ;
    const size_t R1_SZ = (size_t)M_ROWS*4*D_*2;                 // 67,108,864
    const size_t R2 = R1 + R1_SZ;                               // 135,266,304

    __bf16* proj   = (__bf16*)(ws + R0);
    float*  x2     = (float*) (ws + R0);                        // aliases proj (dead)
    __bf16* x2n    = (__bf16*)(ws + R0 + (size_t)M_ROWS*D_*4);
    __bf16* xn     = (__bf16*)(ws + R1);
    __bf16* y2     = (__bf16*)(ws + R1);                        // aliases xn (dead)
    __bf16* u_conv = (__bf16*)(ws + R1 + (size_t)M_ROWS*DIN*2);
    __bf16* h1     = (__bf16*)(ws + R1);                        // aliases y2+u_conv (dead)
    float*  bcraw  = (float*)(ws + R2);                                       // 1 MB
    float*  Bn     = (float*)(ws + R2 + (size_t)M_ROWS*32*4);                 // 0.5 MB
    float*  Cn     = (float*)(ws + R2 + (size_t)M_ROWS*32*4 + (size_t)M_ROWS*16*4);
    float*  dtv    = (float*)(ws + R2 + (size_t)M_ROWS*32*4 + (size_t)M_ROWS*16*4*2);
    float*  Mprod  = (float*)(ws + R2 + (size_t)M_ROWS*32*4*2 + (size_t)M_ROWS*16*4*2); // 1 MB
    __bf16* Wb     = (__bf16*)(ws + R2 + (size_t)M_ROWS*32*4*2 + (size_t)M_ROWS*16*4*2
                                 + (size_t)64*64*16*4*4);       // 8.52 MB slot, reused per GEMM

    float* vbuf = (float*)d_out;   // scan scratch; fully overwritten by fc2 GEMM

    // 1. RMSNorm1 (fp32 x -> bf16 xn)
    rms_kernel<float><<<M_ROWS, 256, 0, stream>>>(x, norm1_w, xn);

    // 2. in_proj GEMM: proj = xn @ in_proj_w^T
    {
        int n = DPROJ*D_;
        cvt_kernel<<<(n/8 + 255)/256, 256, 0, stream>>>(in_proj_w, Wb, n);
        dim3 grid((DPROJ + BN - 1)/BN, M_ROWS/BM);
        gemm_kernel<0><<<grid, 256, 0, stream>>>(xn, Wb, proj, nullptr, nullptr,
                                                 M_ROWS, DPROJ, D_);
    }

    // 3. conv + silu (4-row x 8-channel per thread)
    {
        int total = B_*(L_/4)*(CONVD/8);   // 532,480
        conv_kernel<<<(total + 255)/256, 256, 0, stream>>>(proj, conv_w, conv_b, u_conv, bcraw);
    }

    // 4. B/C normalize + dt softplus
    prep_kernel<<<M_ROWS, 64, 0, stream>>>(bcraw, proj, dt_bias, Bn, Cn, dtv);

    // 5. chunked scan
    {
        int full = B_*H_*NC;   // 4096 (lane-owns-all-n layout)
        scan_phase0<<<B_*H_*16, 64, 0, stream>>>(dtv, A_param, Mprod);
        scan_phase1<<<full, 64, 0, stream>>>(dtv, Bn, u_conv, A_param, vbuf);
        scan_phase2<<<B_*H_*16, 64, 0, stream>>>(vbuf, Mprod);
        scan_phase3<<<full, 64, 0, stream>>>(dtv, Bn, Cn, u_conv, proj, A_param, D_skip,
                                             vbuf, y2);
    }

    // 6. out_proj GEMM + bias + residual(x) -> x2 (fp32, overwrites dead proj)
    {
        int n = D_*DIN;
        cvt_kernel<<<(n/8 + 255)/256, 256, 0, stream>>>(out_proj_w, Wb, n);
        dim3 grid((D_ + BN - 1)/BN, M_ROWS/BM);
        gemm_kernel<2><<<grid, 256, 0, stream>>>(y2, Wb, x2, out_proj_b, x, M_ROWS, D_, DIN);
    }

    // 7. RMSNorm2
    rms_kernel<float><<<M_ROWS, 256, 0, stream>>>(x2, norm2_w, x2n);

    // 8. fc1 GEMM + bias + gelu -> h1 (overwrites dead y2/u_conv)
    {
        int n = 4*D_*D_;
        cvt_kernel<<<(n/8 + 255)/256, 256, 0, stream>>>(fc1_w, Wb, n);
        dim3 grid((4*D_ + BN - 1)/BN, M_ROWS/BM);
        gemm_kernel<3><<<grid, 256, 0, stream>>>(x2n, Wb, h1, fc1_b, nullptr, M_ROWS, 4*D_, D_);
    }

    // 9. fc2 GEMM + bias + residual(x2) -> out (fp32)
    {
        int n = D_*4*D_;
        cvt_kernel<<<(n/8 + 255)/256, 256, 0, stream>>>(fc2_w, Wb, n);
        dim3 grid((D_ + BN - 1)/BN, M_ROWS/BM);
        gemm_kernel<4><<<grid, 256, 0, stream>>>(h1, Wb, out, fc2_b, x2, M_ROWS, D_, 4*D_);
    }
}